// Round 5
// baseline (204.191 us; speedup 1.0000x reference)
//
#include <hip/hip_runtime.h>
#include <stdint.h>
#include <stddef.h>

typedef _Float16 h2 __attribute__((ext_vector_type(2)));
typedef _Float16 h8 __attribute__((ext_vector_type(8)));
typedef float f4 __attribute__((ext_vector_type(4)));

union Hfrag { h2 p[4]; h8 v; };

// ---------------- workspace layout (bytes) ----------------
#define WS_BT     0               // f16 [40 ks][2 half][128 o][32 kk] = 655,360 B
#define WS_SMALL  655360
#define WS_GMIN   (WS_SMALL + 0)      // u32 [256] encoded running min
#define WS_GMAX   (WS_SMALL + 1024)   // u32 [256] encoded running max
#define WS_BKN    (WS_SMALL + 2048)   // f16 [4][256] knot offsets b_j
#define WS_C0     (WS_SMALL + 4096)   // f32 [256] folded constant column
#define WS_BSC    (WS_SMALL + 5120)
#define WS_BSH    (WS_SMALL + 6144)
#define WS_SSC    (WS_SMALL + 7168)
#define WS_SSH    (WS_SMALL + 8192)

// order-preserving float <-> uint32 encoding (monotone for all finite floats)
__device__ __forceinline__ unsigned int fenc(float f) {
  int b = __float_as_int(f);
  return (unsigned int)(b >= 0 ? (b | 0x80000000) : ~b);
}
__device__ __forceinline__ float fdec(unsigned int u) {
  int b = (u & 0x80000000u) ? (int)(u & 0x7FFFFFFFu) : ~(int)u;
  return __int_as_float(b);
}

// ---------------- K1: per-feature min/max -> encoded global atomics ----------
// 512 blocks x 256 threads; block b covers rows b*64..b*64+63.
__global__ __launch_bounds__(256) void kan_minmax(const float* __restrict__ x,
                                                  unsigned int* __restrict__ gmin,
                                                  unsigned int* __restrict__ gmax) {
  __shared__ f4 smn[4][64], smx[4][64];
  const int b = blockIdx.x, t = threadIdx.x;
  const int fq = t & 63, rg = t >> 6;
  const float* p = x + (size_t)b * 64 * 256 + (size_t)rg * 16 * 256 + fq * 4;
  f4 mn = (f4)(3.402823466e38f), mx = (f4)(-3.402823466e38f);
#pragma unroll
  for (int j = 0; j < 16; ++j) {
    f4 v = *(const f4*)(p + (size_t)j * 256);
    mn = __builtin_elementwise_min(mn, v);
    mx = __builtin_elementwise_max(mx, v);
  }
  smn[rg][fq] = mn; smx[rg][fq] = mx;
  __syncthreads();
  if (rg == 0) {
#pragma unroll
    for (int g = 1; g < 4; ++g) {
      mn = __builtin_elementwise_min(mn, smn[g][fq]);
      mx = __builtin_elementwise_max(mx, smx[g][fq]);
    }
#pragma unroll
    for (int j = 0; j < 4; ++j) {
      atomicMin(gmin + fq * 4 + j, fenc(mn[j]));
      atomicMax(gmax + fq * 4 + j, fenc(mx[j]));
    }
  }
}

// ---------------- K3: build reduced f16 weight matrix Bt + all constants -----
// 8 triangle bases on xn in [0,1) span {1, xn, relu(xn-1/4), relu(xn-1/2),
// relu(xn-3/4)}.  Const column -> C0 (folded into spline-BN shift); scale sc
// folds into Bt so GEMM A-columns are relu(x - b_j) on raw x (f16).
// Bt flat: [(ks*2 + half)*128 + o]*32 + kk ; ks = j*8+ic (spline j=0..3),
// ks = 32+ic (base, value = base_w[i, o]).  i = ic*32+kk.
// Also: block 0 writes bkn; thread 0 of block og writes BN consts for og.
__global__ __launch_bounds__(256) void kan_buildw(
    const float* __restrict__ spline_w, const float* __restrict__ spline_s,
    const float* __restrict__ base_w,
    const unsigned int* __restrict__ gmin, const unsigned int* __restrict__ gmax,
    const float* __restrict__ g1, const float* __restrict__ b1,
    const float* __restrict__ m1, const float* __restrict__ v1,
    const float* __restrict__ g2, const float* __restrict__ b2,
    const float* __restrict__ m2, const float* __restrict__ v2,
    _Float16* __restrict__ Bt, _Float16* __restrict__ bkn, float* __restrict__ C0,
    float* __restrict__ bscv, float* __restrict__ bshv,
    float* __restrict__ sscv, float* __restrict__ sshv) {
  const int og = blockIdx.x;   // 256 blocks: one output feature each
  const int i  = threadIdx.x;  // input feature
  const float mnI = fdec(gmin[i]);
  const float mxI = fdec(gmax[i]);
  const float rng = mxI - mnI + 1e-7f;
  const float sc = 1.0f / rng;
  if (og == 0) {
    const float step = 0.25f * rng;
#pragma unroll
    for (int j = 0; j < 4; ++j)
      bkn[j * 256 + i] = (_Float16)(mnI + step * (float)j);
  }
  if (i == 0) {
    const float bs = g1[og] / sqrtf(v1[og] + 1e-3f);
    bscv[og] = bs;
    bshv[og] = b1[og] - m1[og] * bs;
    const float ss = g2[og] / sqrtf(v2[og] + 1e-3f);
    sscv[og] = ss;
    sshv[og] = b2[og] - m2[og] * ss;
  }
  const float* wp = spline_w + (size_t)(og * 256 + i) * 9;
  const float w1 = wp[1], w2 = wp[2], w3 = wp[3], w4 = wp[4];
  const float w5 = wp[5], w6 = wp[6], w7 = wp[7], w8 = wp[8];
  const float s  = spline_s[og * 256 + i];
  const float wp0 = 0.25f*w1 + 0.5f*w2 + 0.75f*w3 + w4 + 0.75f*w5 + 0.5f*w6 + 0.25f*w7;
  float wj[4];
  wj[0] = (w5 + w6 + w7 + w8) - (w1 + w2 + w3 + w4);  // xn column
  wj[1] = w1 - 2.0f * w5;                             // relu(xn-1/4)
  wj[2] = w2 - 2.0f * w6;                             // relu(xn-1/2)
  wj[3] = w3 - 2.0f * w7;                             // relu(xn-3/4)
  const float ssc = s * sc;
  const int half = og >> 7, o = og & 127, ic = i >> 5, kk = i & 31;
#pragma unroll
  for (int j = 0; j < 4; ++j) {
    const int ks = j * 8 + ic;
    Bt[((size_t)(ks * 2 + half) * 128 + o) * 32 + kk] = (_Float16)(wj[j] * ssc);
  }
  Bt[((size_t)((32 + ic) * 2 + half) * 128 + o) * 32 + kk] =
      (_Float16)base_w[(size_t)i * 256 + og];
  __shared__ float red[256];
  red[i] = wp0 * s;
  __syncthreads();
  for (int st = 128; st > 0; st >>= 1) {
    if (i < st) red[i] += red[i + st];
    __syncthreads();
  }
  if (i == 0) C0[og] = red[0];
}

// ---------------- K4: fused dual GEMM + BN + SiLU ----------------
// 64x128 block tile, 4 waves (2x2), per-wave 32 rows x 64 cols (2x4 frags).
// Occupancy: acc = 64 regs (vs 128 at 64x64) -> launch_bounds(256,3) = 3
// waves/SIMD.  Latency decoupling:
//  - bkn staged in LDS at kernel start: bb reads are lgkmcnt, OUTSIDE the
//    vmcnt FIFO (in r0-r4 each bb global-load forced vmcnt~0, draining the
//    B prefetch every substep);
//  - B frags ping-pong 1 substep ahead (vmcnt waits drain only older B);
//  - x prefetch issued after ALL of the chunk's B loads (sched_barrier
//    pinned): newer than every B wait, lands during SPLINE3+base+loop-top.
__global__ __launch_bounds__(256, 3) void kan_gemm(
    const float* __restrict__ x, const _Float16* __restrict__ Bt,
    const _Float16* __restrict__ bkn, const float* __restrict__ C0,
    const float* __restrict__ bscv, const float* __restrict__ bshv,
    const float* __restrict__ sscv, const float* __restrict__ sshv,
    float* __restrict__ out) {
  const int tid = threadIdx.x;
  const int lane = tid & 63;
  const int wv = tid >> 6;
  const int wm = wv >> 1, wn = wv & 1;
  const int lr = lane & 15, lg = lane >> 4;
  const int mt = blockIdx.x & 511, nt = blockIdx.x >> 9;

  const int rowA = mt * 64 + wm * 32 + lr;
  const int colB = wn * 64 + lr;

  __shared__ _Float16 sbkn[1024];
  *(uint2*)(sbkn + tid * 4) = ((const uint2*)bkn)[tid];  // 2048 B cooperative
  __syncthreads();

  f4 accS[2][4], accB[2][4];
#pragma unroll
  for (int m = 0; m < 2; ++m)
#pragma unroll
    for (int n = 0; n < 4; ++n) { accS[m][n] = (f4)0.0f; accB[m][n] = (f4)0.0f; }

  const char* btbase = (const char*)Bt + (size_t)nt * 8192 + (size_t)colB * 64 + (size_t)lg * 16;

  h2 hz; hz[0] = (_Float16)0.0f; hz[1] = (_Float16)0.0f;

  f4 xa[2], xb[2];
  { // prologue: x fragment for ic=0
    const int ib = lg * 8;
#pragma unroll
    for (int m = 0; m < 2; ++m) {
      const float* px = x + (size_t)(rowA + m * 16) * 256 + ib;
      xa[m] = *(const f4*)px; xb[m] = *(const f4*)(px + 4);
    }
  }

#define LOADB(BF, BYTEOFF)                                                   \
  _Pragma("unroll")                                                          \
  for (int n = 0; n < 4; ++n)                                                \
    BF[n].v = *(const h8*)(bpic + (BYTEOFF) + n * 1024);

#define SPLINE_STEP(BB, BF)                                                  \
  {                                                                          \
    _Pragma("unroll")                                                        \
    for (int m = 0; m < 2; ++m) {                                            \
      Hfrag afm;                                                             \
      _Pragma("unroll")                                                      \
      for (int qq = 0; qq < 4; ++qq) {                                       \
        h2 d = xh[m].p[qq] - BB.p[qq];                                       \
        afm.p[qq] = __builtin_elementwise_max(d, hz);                        \
      }                                                                      \
      _Pragma("unroll")                                                      \
      for (int n = 0; n < 4; ++n)                                            \
        accS[m][n] = __builtin_amdgcn_mfma_f32_16x16x32_f16(afm.v, BF[n].v,  \
                                                            accS[m][n], 0, 0, 0); \
    }                                                                        \
  }

#pragma unroll 1
  for (int ic = 0; ic < 8; ++ic) {
    const char* bpic = btbase + (size_t)ic * 16384;

    // knot offsets from LDS (lgkmcnt -- decoupled from the vmcnt FIFO)
    Hfrag bb0, bb1, bb2, bb3;
    bb0.v = *(const h8*)(sbkn +       ic * 32 + lg * 8);
    bb1.v = *(const h8*)(sbkn + 256 + ic * 32 + lg * 8);
    bb2.v = *(const h8*)(sbkn + 512 + ic * 32 + lg * 8);
    bb3.v = *(const h8*)(sbkn + 768 + ic * 32 + lg * 8);

    Hfrag bfA[4], bfB[4];
    LOADB(bfA, 0)                      // ks = ic       (sub-step 0)

    // x -> f16 (RTE); waits only on x loads (older than bfA)
    Hfrag xh[2];
#pragma unroll
    for (int m = 0; m < 2; ++m) {
      xh[m].p[0][0] = (_Float16)xa[m].x; xh[m].p[0][1] = (_Float16)xa[m].y;
      xh[m].p[1][0] = (_Float16)xa[m].z; xh[m].p[1][1] = (_Float16)xa[m].w;
      xh[m].p[2][0] = (_Float16)xb[m].x; xh[m].p[2][1] = (_Float16)xb[m].y;
      xh[m].p[3][0] = (_Float16)xb[m].z; xh[m].p[3][1] = (_Float16)xb[m].w;
    }

    LOADB(bfB, 131072)                 // ks = 8+ic     (sub-step 1)
    SPLINE_STEP(bb0, bfA)
    LOADB(bfA, 262144)                 // ks = 16+ic    (sub-step 2)
    SPLINE_STEP(bb1, bfB)
    LOADB(bfB, 393216)                 // ks = 24+ic    (sub-step 3)
    SPLINE_STEP(bb2, bfA)
    LOADB(bfA, 524288)                 // ks = 32+ic    (base weights)

    // x prefetch for ic+1: issued after ALL B loads of this chunk (FIFO:
    // no B wait will drain it), lands during SPLINE3 + base + loop-top.
    __builtin_amdgcn_sched_barrier(0);
    if (ic < 7) {
      const int ib = (ic + 1) * 32 + lg * 8;
#pragma unroll
      for (int m = 0; m < 2; ++m) {
        const float* px = x + (size_t)(rowA + m * 16) * 256 + ib;
        xa[m] = *(const f4*)px; xb[m] = *(const f4*)(px + 4);
      }
    }

    SPLINE_STEP(bb3, bfB)

    // base sub-step: A = f16(x) verbatim
#pragma unroll
    for (int m = 0; m < 2; ++m)
#pragma unroll
      for (int n = 0; n < 4; ++n)
        accB[m][n] = __builtin_amdgcn_mfma_f32_16x16x32_f16(xh[m].v, bfA[n].v, accB[m][n], 0, 0, 0);
  }
#undef SPLINE_STEP
#undef LOADB

  // epilogue: out = silu(accB*bs + bsh) + accS*ss + (ssh + ss*C0)
#pragma unroll
  for (int n = 0; n < 4; ++n) {
    const int col = nt * 128 + colB + n * 16;
    const float vbs = bscv[col], vbh = bshv[col];
    const float vss = sscv[col];
    const float vsh = sshv[col] + vss * C0[col];
#pragma unroll
    for (int m = 0; m < 2; ++m) {
      const int row0 = mt * 64 + wm * 32 + m * 16 + lg * 4;
#pragma unroll
      for (int r = 0; r < 4; ++r) {
        const float zb = accB[m][n][r] * vbs + vbh;
        const float si = zb / (1.0f + __expf(-zb));
        const float val = si + accS[m][n][r] * vss + vsh;
        out[(size_t)(row0 + r) * 256 + col] = val;
      }
    }
  }
}

extern "C" void kernel_launch(void* const* d_in, const int* in_sizes, int n_in,
                              void* d_out, int out_size, void* d_ws, size_t ws_size,
                              hipStream_t stream) {
  const float* x        = (const float*)d_in[0];
  const float* base_w   = (const float*)d_in[1];
  const float* spline_w = (const float*)d_in[2];
  const float* spline_s = (const float*)d_in[3];
  const float* g1 = (const float*)d_in[4];
  const float* b1 = (const float*)d_in[5];
  const float* m1 = (const float*)d_in[6];
  const float* v1 = (const float*)d_in[7];
  const float* g2 = (const float*)d_in[8];
  const float* b2 = (const float*)d_in[9];
  const float* m2 = (const float*)d_in[10];
  const float* v2 = (const float*)d_in[11];
  float* out = (float*)d_out;
  char* ws = (char*)d_ws;

  _Float16* Bt      = (_Float16*)(ws + WS_BT);
  unsigned int* gmn = (unsigned int*)(ws + WS_GMIN);
  unsigned int* gmx = (unsigned int*)(ws + WS_GMAX);
  _Float16* bkn     = (_Float16*)(ws + WS_BKN);
  float* C0         = (float*)(ws + WS_C0);
  float* bscv       = (float*)(ws + WS_BSC);
  float* bshv       = (float*)(ws + WS_BSH);
  float* sscv       = (float*)(ws + WS_SSC);
  float* sshv       = (float*)(ws + WS_SSH);

  hipMemsetAsync(ws + WS_GMIN, 0xFF, 1024, stream);  // enc-min init = UINT_MAX
  hipMemsetAsync(ws + WS_GMAX, 0x00, 1024, stream);  // enc-max init = 0
  kan_minmax<<<512, 256, 0, stream>>>(x, gmn, gmx);
  kan_buildw<<<256, 256, 0, stream>>>(spline_w, spline_s, base_w, gmn, gmx,
                                      g1, b1, m1, v1, g2, b2, m2, v2,
                                      Bt, bkn, C0, bscv, bshv, sscv, sshv);
  kan_gemm<<<1024, 256, 0, stream>>>(x, Bt, bkn, C0, bscv, bshv, sscv, sshv, out);
}

// Round 6
// 182.992 us; speedup vs baseline: 1.1159x; 1.1159x over previous
//
#include <hip/hip_runtime.h>
#include <stdint.h>
#include <stddef.h>

typedef _Float16 h2 __attribute__((ext_vector_type(2)));
typedef _Float16 h8 __attribute__((ext_vector_type(8)));
typedef float f4 __attribute__((ext_vector_type(4)));

union Hfrag { h2 p[4]; h8 v; };

// ---------------- workspace layout (bytes) ----------------
// pmin/pmax (K1 partials) are dead after K2; Bt (built in K3) overlays pmin.
#define WS_PMIN   0               // f32 [512][256] = 512 KB
#define WS_PMAX   524288          // f32 [512][256] = 512 KB
#define WS_BT     0               // f16 [40 ks][2 half][128 o][32 kk] = 655,360 B
#define WS_SMALL  1048576
#define WS_SCALEV (WS_SMALL + 0)      // f32 [256]
#define WS_BKN    (WS_SMALL + 1024)   // f16 [4][256] knot offsets b_j
#define WS_C0     (WS_SMALL + 3072)   // f32 [256] folded constant column
#define WS_BSC    (WS_SMALL + 4096)
#define WS_BSH    (WS_SMALL + 5120)
#define WS_SSC    (WS_SMALL + 6144)
#define WS_SSH    (WS_SMALL + 7168)

// ---------------- K1: per-feature min/max partials ----------------
__global__ __launch_bounds__(256) void kan_minmax(const float* __restrict__ x,
                                                  float* __restrict__ pmin,
                                                  float* __restrict__ pmax) {
  __shared__ f4 smn[4][64], smx[4][64];
  const int b = blockIdx.x, t = threadIdx.x;
  const int fq = t & 63, rg = t >> 6;
  const float* p = x + (size_t)b * 64 * 256 + (size_t)rg * 16 * 256 + fq * 4;
  f4 mn = (f4)(3.402823466e38f), mx = (f4)(-3.402823466e38f);
#pragma unroll
  for (int j = 0; j < 16; ++j) {
    f4 v = *(const f4*)(p + (size_t)j * 256);
    mn = __builtin_elementwise_min(mn, v);
    mx = __builtin_elementwise_max(mx, v);
  }
  smn[rg][fq] = mn; smx[rg][fq] = mx;
  __syncthreads();
  if (rg == 0) {
#pragma unroll
    for (int g = 1; g < 4; ++g) {
      mn = __builtin_elementwise_min(mn, smn[g][fq]);
      mx = __builtin_elementwise_max(mx, smx[g][fq]);
    }
    *(f4*)(pmin + (size_t)b * 256 + fq * 4) = mn;
    *(f4*)(pmax + (size_t)b * 256 + fq * 4) = mx;
  }
}

// ---------------- K2: finalize minmax -> scalev, knot offsets, BN consts ----
// 64 blocks x 256 threads; block q covers features 4q..4q+3 (f4 columns).
__global__ __launch_bounds__(256) void kan_finalize(
    const float* __restrict__ pmin, const float* __restrict__ pmax,
    const float* __restrict__ g1, const float* __restrict__ b1,
    const float* __restrict__ m1, const float* __restrict__ v1,
    const float* __restrict__ g2, const float* __restrict__ b2,
    const float* __restrict__ m2, const float* __restrict__ v2,
    float* __restrict__ scalev, _Float16* __restrict__ bkn,
    float* __restrict__ bscv, float* __restrict__ bshv,
    float* __restrict__ sscv, float* __restrict__ sshv) {
  __shared__ f4 smn[256], smx[256];
  const int t = threadIdx.x, q = blockIdx.x;
  const float* pm = pmin + (size_t)t * 256 + q * 4;
  const float* px = pmax + (size_t)t * 256 + q * 4;
  f4 mn = __builtin_elementwise_min(*(const f4*)pm, *(const f4*)(pm + 256 * 256));
  f4 mx = __builtin_elementwise_max(*(const f4*)px, *(const f4*)(px + 256 * 256));
  smn[t] = mn; smx[t] = mx;
  __syncthreads();
  for (int st = 128; st > 0; st >>= 1) {
    if (t < st) {
      smn[t] = __builtin_elementwise_min(smn[t], smn[t + st]);
      smx[t] = __builtin_elementwise_max(smx[t], smx[t + st]);
    }
    __syncthreads();
  }
  if (t == 0) {
    const f4 fmn = smn[0], fmx = smx[0];
#pragma unroll
    for (int j = 0; j < 4; ++j) {
      const int o = q * 4 + j;
      const float mnS = fmn[j], mxS = fmx[j];
      const float rng = mxS - mnS + 1e-7f;
      scalev[o] = 1.0f / rng;
      const float step = 0.25f * rng;
#pragma unroll
      for (int jj = 0; jj < 4; ++jj)
        bkn[jj * 256 + o] = (_Float16)(mnS + step * (float)jj);
      const float bs = g1[o] / sqrtf(v1[o] + 1e-3f);
      bscv[o] = bs;
      bshv[o] = b1[o] - m1[o] * bs;
      const float ss = g2[o] / sqrtf(v2[o] + 1e-3f);
      sscv[o] = ss;
      sshv[o] = b2[o] - m2[o] * ss;
    }
  }
}

// ---------------- K3: build reduced f16 weight matrix Bt + C0 ----------------
// 8 triangle bases on xn in [0,1) span {1, xn, relu(xn-1/4), relu(xn-1/2),
// relu(xn-3/4)}.  Const column -> C0 (folded into spline-BN shift); scale sc
// folds into Bt so GEMM A-columns are relu(x - b_j) on raw x (f16).
// Bt flat: [(ks*2 + half)*128 + o]*32 + kk ; ks = j*8+ic (spline j=0..3),
// ks = 32+ic (base, value = base_w[i, o]).  i = ic*32+kk.
__global__ __launch_bounds__(256) void kan_buildw(
    const float* __restrict__ spline_w, const float* __restrict__ spline_s,
    const float* __restrict__ base_w, const float* __restrict__ scalev,
    _Float16* __restrict__ Bt, float* __restrict__ C0) {
  const int og = blockIdx.x;   // 256 blocks: one output feature each
  const int i  = threadIdx.x;  // input feature
  const float* wp = spline_w + (size_t)(og * 256 + i) * 9;
  const float w1 = wp[1], w2 = wp[2], w3 = wp[3], w4 = wp[4];
  const float w5 = wp[5], w6 = wp[6], w7 = wp[7], w8 = wp[8];
  const float s  = spline_s[og * 256 + i];
  const float sc = scalev[i];
  const float wp0 = 0.25f*w1 + 0.5f*w2 + 0.75f*w3 + w4 + 0.75f*w5 + 0.5f*w6 + 0.25f*w7;
  float wj[4];
  wj[0] = (w5 + w6 + w7 + w8) - (w1 + w2 + w3 + w4);  // xn column
  wj[1] = w1 - 2.0f * w5;                             // relu(xn-1/4)
  wj[2] = w2 - 2.0f * w6;                             // relu(xn-1/2)
  wj[3] = w3 - 2.0f * w7;                             // relu(xn-3/4)
  const float ssc = s * sc;
  const int half = og >> 7, o = og & 127, ic = i >> 5, kk = i & 31;
#pragma unroll
  for (int j = 0; j < 4; ++j) {
    const int ks = j * 8 + ic;
    Bt[((size_t)(ks * 2 + half) * 128 + o) * 32 + kk] = (_Float16)(wj[j] * ssc);
  }
  Bt[((size_t)((32 + ic) * 2 + half) * 128 + o) * 32 + kk] =
      (_Float16)base_w[(size_t)i * 256 + og];
  __shared__ float red[256];
  red[i] = wp0 * s;
  __syncthreads();
  for (int st = 128; st > 0; st >>= 1) {
    if (i < st) red[i] += red[i + st];
    __syncthreads();
  }
  if (i == 0) C0[og] = red[0];
}

// ---------------- K4: fused dual GEMM + BN + SiLU ----------------
// 64x128 block tile, 4 waves side-by-side in N (wn=wv), per-wave 64 rows x
// 32 cols (m=4, n=2).  Same structure as the 50.4us r4 kernel; single axis
// changed: dual acc = 64 regs (not 128) + bkn in LDS + per-substep bbj ->
// arch VGPR ~90, total ~155 <= 170 -> REAL 3 waves/SIMD (r5 asked for 3 but
// 204 total regs silently kept it at 2, while also halving B amortization;
// here MFMA:B-load stays 4:1).
__global__ __launch_bounds__(256, 3) void kan_gemm(
    const float* __restrict__ x, const _Float16* __restrict__ Bt,
    const _Float16* __restrict__ bkn, const float* __restrict__ C0,
    const float* __restrict__ bscv, const float* __restrict__ bshv,
    const float* __restrict__ sscv, const float* __restrict__ sshv,
    float* __restrict__ out) {
  const int tid = threadIdx.x;
  const int lane = tid & 63;
  const int wn = tid >> 6;                 // wave = N-slice
  const int lr = lane & 15, lg = lane >> 4;
  const int mt = blockIdx.x & 511, nt = blockIdx.x >> 9;

  const int rowA = mt * 64 + lr;           // + 16*m
  const int colB = wn * 32 + lr;           // + 16*n, global +nt*128

  __shared__ _Float16 sbkn[1024];
  *(uint2*)(sbkn + tid * 4) = ((const uint2*)bkn)[tid];  // 2 KB cooperative
  __syncthreads();

  f4 accS[4][2], accB[4][2];
#pragma unroll
  for (int m = 0; m < 4; ++m)
#pragma unroll
    for (int n = 0; n < 2; ++n) { accS[m][n] = (f4)0.0f; accB[m][n] = (f4)0.0f; }

  const char* btbase = (const char*)Bt + (size_t)nt * 8192 + (size_t)colB * 64 + (size_t)lg * 16;

  h2 hz; hz[0] = (_Float16)0.0f; hz[1] = (_Float16)0.0f;

  f4 xa[4], xb[4];
  { // prologue: x fragment for ic=0
    const int ib = lg * 8;
#pragma unroll
    for (int m = 0; m < 4; ++m) {
      const float* px = x + (size_t)(rowA + m * 16) * 256 + ib;
      xa[m] = *(const f4*)px; xb[m] = *(const f4*)(px + 4);
    }
  }

#define LOADB(BF, BYTEOFF)                                                   \
  _Pragma("unroll")                                                          \
  for (int n = 0; n < 2; ++n)                                                \
    BF[n].v = *(const h8*)(bpic + (BYTEOFF) + n * 1024);

// bbj read per-substep from LDS (lgkmcnt, outside the vmcnt FIFO; short live
// range keeps arch VGPRs down for the 3-wave budget)
#define SPLINE_STEP(J, BF)                                                   \
  {                                                                          \
    Hfrag bbj;                                                               \
    bbj.v = *(const h8*)(sbkn + (J) * 256 + ic * 32 + lg * 8);               \
    _Pragma("unroll")                                                        \
    for (int m = 0; m < 4; ++m) {                                            \
      Hfrag afm;                                                             \
      _Pragma("unroll")                                                      \
      for (int qq = 0; qq < 4; ++qq) {                                       \
        h2 d = xh[m].p[qq] - bbj.p[qq];                                      \
        afm.p[qq] = __builtin_elementwise_max(d, hz);                        \
      }                                                                      \
      _Pragma("unroll")                                                      \
      for (int n = 0; n < 2; ++n)                                            \
        accS[m][n] = __builtin_amdgcn_mfma_f32_16x16x32_f16(afm.v, BF[n].v,  \
                                                            accS[m][n], 0, 0, 0); \
    }                                                                        \
  }

#pragma unroll 1
  for (int ic = 0; ic < 8; ++ic) {
    const char* bpic = btbase + (size_t)ic * 16384;

    Hfrag bfA[2], bfB[2];
    LOADB(bfA, 0)                      // ks = ic       (sub-step 0)

    // x -> f16 (RTE), A-fragment layout
    Hfrag xh[4];
#pragma unroll
    for (int m = 0; m < 4; ++m) {
      xh[m].p[0][0] = (_Float16)xa[m].x; xh[m].p[0][1] = (_Float16)xa[m].y;
      xh[m].p[1][0] = (_Float16)xa[m].z; xh[m].p[1][1] = (_Float16)xa[m].w;
      xh[m].p[2][0] = (_Float16)xb[m].x; xh[m].p[2][1] = (_Float16)xb[m].y;
      xh[m].p[3][0] = (_Float16)xb[m].z; xh[m].p[3][1] = (_Float16)xb[m].w;
    }

    LOADB(bfB, 131072)                 // ks = 8+ic     (sub-step 1)
    SPLINE_STEP(0, bfA)
    LOADB(bfA, 262144)                 // ks = 16+ic    (sub-step 2)
    SPLINE_STEP(1, bfB)
    LOADB(bfB, 393216)                 // ks = 24+ic    (sub-step 3)
    SPLINE_STEP(2, bfA)
    LOADB(bfA, 524288)                 // ks = 32+ic    (base weights)

    // x prefetch for ic+1 after ALL B loads of this chunk (vmcnt FIFO:
    // no B-frag wait will be forced to drain these HBM loads)
    __builtin_amdgcn_sched_barrier(0);
    if (ic < 7) {
      const int ib = (ic + 1) * 32 + lg * 8;
#pragma unroll
      for (int m = 0; m < 4; ++m) {
        const float* px = x + (size_t)(rowA + m * 16) * 256 + ib;
        xa[m] = *(const f4*)px; xb[m] = *(const f4*)(px + 4);
      }
    }

    SPLINE_STEP(3, bfB)

    // base sub-step: A = f16(x) verbatim
#pragma unroll
    for (int m = 0; m < 4; ++m)
#pragma unroll
      for (int n = 0; n < 2; ++n)
        accB[m][n] = __builtin_amdgcn_mfma_f32_16x16x32_f16(xh[m].v, bfA[n].v, accB[m][n], 0, 0, 0);
  }
#undef SPLINE_STEP
#undef LOADB

  // epilogue: out = silu(accB*bs + bsh) + accS*ss + (ssh + ss*C0)
#pragma unroll
  for (int n = 0; n < 2; ++n) {
    const int col = nt * 128 + colB + n * 16;
    const float vbs = bscv[col], vbh = bshv[col];
    const float vss = sscv[col];
    const float vsh = sshv[col] + vss * C0[col];
#pragma unroll
    for (int m = 0; m < 4; ++m) {
      const int row0 = mt * 64 + m * 16 + lg * 4;
#pragma unroll
      for (int r = 0; r < 4; ++r) {
        const float zb = accB[m][n][r] * vbs + vbh;
        const float si = zb / (1.0f + __expf(-zb));
        const float val = si + accS[m][n][r] * vss + vsh;
        out[(size_t)(row0 + r) * 256 + col] = val;
      }
    }
  }
}

extern "C" void kernel_launch(void* const* d_in, const int* in_sizes, int n_in,
                              void* d_out, int out_size, void* d_ws, size_t ws_size,
                              hipStream_t stream) {
  const float* x        = (const float*)d_in[0];
  const float* base_w   = (const float*)d_in[1];
  const float* spline_w = (const float*)d_in[2];
  const float* spline_s = (const float*)d_in[3];
  const float* g1 = (const float*)d_in[4];
  const float* b1 = (const float*)d_in[5];
  const float* m1 = (const float*)d_in[6];
  const float* v1 = (const float*)d_in[7];
  const float* g2 = (const float*)d_in[8];
  const float* b2 = (const float*)d_in[9];
  const float* m2 = (const float*)d_in[10];
  const float* v2 = (const float*)d_in[11];
  float* out = (float*)d_out;
  char* ws = (char*)d_ws;

  float* pmin     = (float*)(ws + WS_PMIN);
  float* pmax     = (float*)(ws + WS_PMAX);
  _Float16* Bt    = (_Float16*)(ws + WS_BT);
  float* scalev   = (float*)(ws + WS_SCALEV);
  _Float16* bkn   = (_Float16*)(ws + WS_BKN);
  float* C0       = (float*)(ws + WS_C0);
  float* bscv     = (float*)(ws + WS_BSC);
  float* bshv     = (float*)(ws + WS_BSH);
  float* sscv     = (float*)(ws + WS_SSC);
  float* sshv     = (float*)(ws + WS_SSH);

  kan_minmax<<<512, 256, 0, stream>>>(x, pmin, pmax);
  kan_finalize<<<64, 256, 0, stream>>>(pmin, pmax, g1, b1, m1, v1, g2, b2, m2, v2,
                                       scalev, bkn, bscv, bshv, sscv, sshv);
  kan_buildw<<<256, 256, 0, stream>>>(spline_w, spline_s, base_w, scalev, Bt, C0);
  kan_gemm<<<1024, 256, 0, stream>>>(x, Bt, bkn, C0, bscv, bshv, sscv, sshv, out);
}

// Round 7
// 143.620 us; speedup vs baseline: 1.4217x; 1.2741x over previous
//
#include <hip/hip_runtime.h>
#include <stdint.h>
#include <stddef.h>

typedef _Float16 h2 __attribute__((ext_vector_type(2)));
typedef _Float16 h8 __attribute__((ext_vector_type(8)));
typedef float f4 __attribute__((ext_vector_type(4)));

union Hfrag { h2 p[4]; h8 v; };

// ---------------- workspace layout (bytes) ----------------
// pmin/pmax (K1 partials) are dead after K2; Bt (built in K3) overlays them.
// Bt layout (STAGED-GEMM form, padded rows):
//   [ic 0..7][half 0..1][j 0..4][o 0..127][80 B row: 64 B data (kk*2) + 16 pad]
//   j = 0..3 spline cols, j = 4 base weights.  Total 1,024,000 B.
//   Row stride 80 B -> LDS bank stride 20 dwords -> uniform 8 dwords/bank for
//   ds_read_b128 across a wave (provably optimal; no XOR swizzle needed).
#define WS_PMIN   0               // f32 [512][256] = 512 KB
#define WS_PMAX   524288          // f32 [512][256] = 512 KB
#define WS_BT     0               // 1,024,000 B (overlays pmin+pmax)
#define WS_SMALL  1048576
#define WS_SCALEV (WS_SMALL + 0)      // f32 [256]
#define WS_BKN    (WS_SMALL + 1024)   // f16 [4][256] knot offsets b_j
#define WS_C0     (WS_SMALL + 3072)   // f32 [256] folded constant column
#define WS_BSC    (WS_SMALL + 4096)
#define WS_BSH    (WS_SMALL + 5120)
#define WS_SSC    (WS_SMALL + 6144)
#define WS_SSH    (WS_SMALL + 7168)

__device__ __forceinline__ void gload_lds16(const void* g, void* l) {
  __builtin_amdgcn_global_load_lds(
      (const __attribute__((address_space(1))) void*)g,
      (__attribute__((address_space(3))) void*)l, 16, 0, 0);
}

// ---------------- K1: per-feature min/max partials ----------------
__global__ __launch_bounds__(256) void kan_minmax(const float* __restrict__ x,
                                                  float* __restrict__ pmin,
                                                  float* __restrict__ pmax) {
  __shared__ f4 smn[4][64], smx[4][64];
  const int b = blockIdx.x, t = threadIdx.x;
  const int fq = t & 63, rg = t >> 6;
  const float* p = x + (size_t)b * 64 * 256 + (size_t)rg * 16 * 256 + fq * 4;
  f4 mn = (f4)(3.402823466e38f), mx = (f4)(-3.402823466e38f);
#pragma unroll
  for (int j = 0; j < 16; ++j) {
    f4 v = *(const f4*)(p + (size_t)j * 256);
    mn = __builtin_elementwise_min(mn, v);
    mx = __builtin_elementwise_max(mx, v);
  }
  smn[rg][fq] = mn; smx[rg][fq] = mx;
  __syncthreads();
  if (rg == 0) {
#pragma unroll
    for (int g = 1; g < 4; ++g) {
      mn = __builtin_elementwise_min(mn, smn[g][fq]);
      mx = __builtin_elementwise_max(mx, smx[g][fq]);
    }
    *(f4*)(pmin + (size_t)b * 256 + fq * 4) = mn;
    *(f4*)(pmax + (size_t)b * 256 + fq * 4) = mx;
  }
}

// ---------------- K2: finalize minmax -> scalev, knot offsets, BN consts ----
// 64 blocks x 256 threads; block q covers features 4q..4q+3 (f4 columns).
__global__ __launch_bounds__(256) void kan_finalize(
    const float* __restrict__ pmin, const float* __restrict__ pmax,
    const float* __restrict__ g1, const float* __restrict__ b1,
    const float* __restrict__ m1, const float* __restrict__ v1,
    const float* __restrict__ g2, const float* __restrict__ b2,
    const float* __restrict__ m2, const float* __restrict__ v2,
    float* __restrict__ scalev, _Float16* __restrict__ bkn,
    float* __restrict__ bscv, float* __restrict__ bshv,
    float* __restrict__ sscv, float* __restrict__ sshv) {
  __shared__ f4 smn[256], smx[256];
  const int t = threadIdx.x, q = blockIdx.x;
  const float* pm = pmin + (size_t)t * 256 + q * 4;
  const float* px = pmax + (size_t)t * 256 + q * 4;
  f4 mn = __builtin_elementwise_min(*(const f4*)pm, *(const f4*)(pm + 256 * 256));
  f4 mx = __builtin_elementwise_max(*(const f4*)px, *(const f4*)(px + 256 * 256));
  smn[t] = mn; smx[t] = mx;
  __syncthreads();
  for (int st = 128; st > 0; st >>= 1) {
    if (t < st) {
      smn[t] = __builtin_elementwise_min(smn[t], smn[t + st]);
      smx[t] = __builtin_elementwise_max(smx[t], smx[t + st]);
    }
    __syncthreads();
  }
  if (t == 0) {
    const f4 fmn = smn[0], fmx = smx[0];
#pragma unroll
    for (int j = 0; j < 4; ++j) {
      const int o = q * 4 + j;
      const float mnS = fmn[j], mxS = fmx[j];
      const float rng = mxS - mnS + 1e-7f;
      scalev[o] = 1.0f / rng;
      const float step = 0.25f * rng;
#pragma unroll
      for (int jj = 0; jj < 4; ++jj)
        bkn[jj * 256 + o] = (_Float16)(mnS + step * (float)jj);
      const float bs = g1[o] / sqrtf(v1[o] + 1e-3f);
      bscv[o] = bs;
      bshv[o] = b1[o] - m1[o] * bs;
      const float ss = g2[o] / sqrtf(v2[o] + 1e-3f);
      sscv[o] = ss;
      sshv[o] = b2[o] - m2[o] * ss;
    }
  }
}

// ---------------- K3: build reduced f16 weight matrix Bt + C0 ----------------
// 8 triangle bases on xn in [0,1) span {1, xn, relu(xn-1/4), relu(xn-1/2),
// relu(xn-3/4)}.  Const column -> C0 (folded into spline-BN shift); scale sc
// folds into Bt so GEMM A-columns are relu(x - b_j) on raw x (f16).
// Bt half-index = ic*64000 + half*25600 + j*5120 + o*40 + kk
//   (ic = i>>5, kk = i&31, half = og>>7, o = og&127; j=4 is base_w[i,o]).
__global__ __launch_bounds__(256) void kan_buildw(
    const float* __restrict__ spline_w, const float* __restrict__ spline_s,
    const float* __restrict__ base_w, const float* __restrict__ scalev,
    _Float16* __restrict__ Bt, float* __restrict__ C0) {
  const int og = blockIdx.x;   // 256 blocks: one output feature each
  const int i  = threadIdx.x;  // input feature
  const float* wp = spline_w + (size_t)(og * 256 + i) * 9;
  const float w1 = wp[1], w2 = wp[2], w3 = wp[3], w4 = wp[4];
  const float w5 = wp[5], w6 = wp[6], w7 = wp[7], w8 = wp[8];
  const float s  = spline_s[og * 256 + i];
  const float sc = scalev[i];
  const float wp0 = 0.25f*w1 + 0.5f*w2 + 0.75f*w3 + w4 + 0.75f*w5 + 0.5f*w6 + 0.25f*w7;
  float wj[4];
  wj[0] = (w5 + w6 + w7 + w8) - (w1 + w2 + w3 + w4);  // xn column
  wj[1] = w1 - 2.0f * w5;                             // relu(xn-1/4)
  wj[2] = w2 - 2.0f * w6;                             // relu(xn-1/2)
  wj[3] = w3 - 2.0f * w7;                             // relu(xn-3/4)
  const float ssc = s * sc;
  const int half = og >> 7, o = og & 127, ic = i >> 5, kk = i & 31;
  const size_t base = (size_t)ic * 64000 + (size_t)half * 25600 + (size_t)o * 40 + kk;
#pragma unroll
  for (int j = 0; j < 4; ++j)
    Bt[base + (size_t)j * 5120] = (_Float16)(wj[j] * ssc);
  Bt[base + 4 * 5120] = (_Float16)base_w[(size_t)i * 256 + og];
  __shared__ float red[256];
  red[i] = wp0 * s;
  __syncthreads();
  for (int st = 128; st > 0; st >>= 1) {
    if (i < st) red[i] += red[i + st];
    __syncthreads();
  }
  if (i == 0) C0[og] = red[0];
}

// ---------------- K4: fused dual GEMM + BN + SiLU (LDS-staged B) ------------
// r4 tile restored: 128x128 block, 4 waves 2x2, per-wave 64x64 (m=4,n=4),
// 16-MFMA substeps (the proven best MFMA:wait ratio).  NEW: per chunk the
// block bulk-stages its 50 KB B slice (5 j-groups, its nt half) into LDS via
// global_load_lds -> ONE vmcnt(0)+barrier per chunk instead of 5 latency-
// exposed L2 waits, and kills the wn-duplicate L2 loads.  ds_read_b128 feeds
// the MFMAs (lgkm, decoupled from vmcnt); 80 B row stride = conflict-free.
__global__ __launch_bounds__(256, 2) void kan_gemm(
    const float* __restrict__ x, const _Float16* __restrict__ Bt,
    const _Float16* __restrict__ bkn, const float* __restrict__ C0,
    const float* __restrict__ bscv, const float* __restrict__ bshv,
    const float* __restrict__ sscv, const float* __restrict__ sshv,
    float* __restrict__ out) {
  const int tid = threadIdx.x;
  const int lane = tid & 63;
  const int wv = tid >> 6;
  const int wm = wv >> 1, wn = wv & 1;
  const int lr = lane & 15, lg = lane >> 4;
  const int mt = blockIdx.x & 255, nt = blockIdx.x >> 8;

  const int rowA = mt * 128 + wm * 64 + lr;
  const int colB = wn * 64 + lr;

  __shared__ __align__(16) char smem[53248];     // 51200 stage + 2048 sbkn
  _Float16* sbkn = (_Float16*)(smem + 51200);
  *(uint2*)(sbkn + tid * 4) = ((const uint2*)bkn)[tid];

  f4 accS[4][4], accB[4][4];
#pragma unroll
  for (int m = 0; m < 4; ++m)
#pragma unroll
    for (int n = 0; n < 4; ++n) { accS[m][n] = (f4)0.0f; accB[m][n] = (f4)0.0f; }

  h2 hz; hz[0] = (_Float16)0.0f; hz[1] = (_Float16)0.0f;

  const int rowb = colB * 80 + lg * 16;          // per-lane LDS row base (bytes)

  f4 xa[4], xb[4];
  { // prologue: x fragment for ic=0
    const int ib = lg * 8;
#pragma unroll
    for (int m = 0; m < 4; ++m) {
      const float* px = x + (size_t)(rowA + m * 16) * 256 + ib;
      xa[m] = *(const f4*)px; xb[m] = *(const f4*)(px + 4);
    }
  }

// B frags from LDS: j-group J, frag n at rowb + J*10240 + n*1280 (imm offset)
#define LOADB(BF, J)                                                         \
  _Pragma("unroll")                                                          \
  for (int n = 0; n < 4; ++n)                                                \
    BF[n].v = *(const h8*)(smem + rowb + (J) * 10240 + n * 1280);

#define SPLINE_STEP(J, BF)                                                   \
  {                                                                          \
    Hfrag bbj;                                                               \
    bbj.v = *(const h8*)(sbkn + (J) * 256 + ic * 32 + lg * 8);               \
    _Pragma("unroll")                                                        \
    for (int m = 0; m < 4; ++m) {                                            \
      Hfrag afm;                                                             \
      _Pragma("unroll")                                                      \
      for (int qq = 0; qq < 4; ++qq) {                                       \
        h2 d = xh[m].p[qq] - bbj.p[qq];                                      \
        afm.p[qq] = __builtin_elementwise_max(d, hz);                        \
      }                                                                      \
      _Pragma("unroll")                                                      \
      for (int n = 0; n < 4; ++n)                                            \
        accS[m][n] = __builtin_amdgcn_mfma_f32_16x16x32_f16(afm.v, BF[n].v,  \
                                                            accS[m][n], 0, 0, 0); \
    }                                                                        \
  }

#pragma unroll 1
  for (int ic = 0; ic < 8; ++ic) {
    __syncthreads();   // previous chunk's ds_reads done before overwrite
                       // (ic=0: covers sbkn visibility)
    { // stage 50 KB: [5 j][128 o][80 B] of (ic, half=nt), linear copy
      const char* gsrc = (const char*)Bt + (size_t)ic * 128000 + (size_t)nt * 51200;
#pragma unroll
      for (int r = 0; r < 13; ++r) {
        const int idx = r * 256 + tid;
        if (idx < 3200)
          gload_lds16(gsrc + (size_t)idx * 16, smem + r * 4096 + wv * 1024);
      }
    }
    asm volatile("s_waitcnt vmcnt(0)" ::: "memory");
    __syncthreads();

    // x -> f16 (RTE), A-fragment layout (current chunk)
    Hfrag xh[4];
#pragma unroll
    for (int m = 0; m < 4; ++m) {
      xh[m].p[0][0] = (_Float16)xa[m].x; xh[m].p[0][1] = (_Float16)xa[m].y;
      xh[m].p[1][0] = (_Float16)xa[m].z; xh[m].p[1][1] = (_Float16)xa[m].w;
      xh[m].p[2][0] = (_Float16)xb[m].x; xh[m].p[2][1] = (_Float16)xb[m].y;
      xh[m].p[3][0] = (_Float16)xb[m].z; xh[m].p[3][1] = (_Float16)xb[m].w;
    }

    // x prefetch for ic+1, pinned at compute start: its ~900cy HBM latency
    // hides under this chunk's 5 substeps, drained by next chunk's vmcnt(0).
    __builtin_amdgcn_sched_barrier(0);
    if (ic < 7) {
      const int ib = (ic + 1) * 32 + lg * 8;
#pragma unroll
      for (int m = 0; m < 4; ++m) {
        const float* px = x + (size_t)(rowA + m * 16) * 256 + ib;
        xa[m] = *(const f4*)px; xb[m] = *(const f4*)(px + 4);
      }
    }
    __builtin_amdgcn_sched_barrier(0);

    Hfrag bfA[4], bfB[4];
    LOADB(bfA, 0)
    LOADB(bfB, 1)
    SPLINE_STEP(0, bfA)
    LOADB(bfA, 2)
    SPLINE_STEP(1, bfB)
    LOADB(bfB, 3)
    SPLINE_STEP(2, bfA)
    LOADB(bfA, 4)                      // base weights
    SPLINE_STEP(3, bfB)

    // base sub-step: A = f16(x) verbatim
#pragma unroll
    for (int m = 0; m < 4; ++m)
#pragma unroll
      for (int n = 0; n < 4; ++n)
        accB[m][n] = __builtin_amdgcn_mfma_f32_16x16x32_f16(xh[m].v, bfA[n].v, accB[m][n], 0, 0, 0);
  }
#undef SPLINE_STEP
#undef LOADB

  // epilogue: out = silu(accB*bs + bsh) + accS*ss + (ssh + ss*C0)
#pragma unroll
  for (int n = 0; n < 4; ++n) {
    const int col = nt * 128 + colB + n * 16;
    const float vbs = bscv[col], vbh = bshv[col];
    const float vss = sscv[col];
    const float vsh = sshv[col] + vss * C0[col];
#pragma unroll
    for (int m = 0; m < 4; ++m) {
      const int row0 = mt * 128 + wm * 64 + m * 16 + lg * 4;
#pragma unroll
      for (int r = 0; r < 4; ++r) {
        const float zb = accB[m][n][r] * vbs + vbh;
        const float si = zb / (1.0f + __expf(-zb));
        const float val = si + accS[m][n][r] * vss + vsh;
        out[(size_t)(row0 + r) * 256 + col] = val;
      }
    }
  }
}

extern "C" void kernel_launch(void* const* d_in, const int* in_sizes, int n_in,
                              void* d_out, int out_size, void* d_ws, size_t ws_size,
                              hipStream_t stream) {
  const float* x        = (const float*)d_in[0];
  const float* base_w   = (const float*)d_in[1];
  const float* spline_w = (const float*)d_in[2];
  const float* spline_s = (const float*)d_in[3];
  const float* g1 = (const float*)d_in[4];
  const float* b1 = (const float*)d_in[5];
  const float* m1 = (const float*)d_in[6];
  const float* v1 = (const float*)d_in[7];
  const float* g2 = (const float*)d_in[8];
  const float* b2 = (const float*)d_in[9];
  const float* m2 = (const float*)d_in[10];
  const float* v2 = (const float*)d_in[11];
  float* out = (float*)d_out;
  char* ws = (char*)d_ws;

  float* pmin     = (float*)(ws + WS_PMIN);
  float* pmax     = (float*)(ws + WS_PMAX);
  _Float16* Bt    = (_Float16*)(ws + WS_BT);
  float* scalev   = (float*)(ws + WS_SCALEV);
  _Float16* bkn   = (_Float16*)(ws + WS_BKN);
  float* C0       = (float*)(ws + WS_C0);
  float* bscv     = (float*)(ws + WS_BSC);
  float* bshv     = (float*)(ws + WS_BSH);
  float* sscv     = (float*)(ws + WS_SSC);
  float* sshv     = (float*)(ws + WS_SSH);

  kan_minmax<<<512, 256, 0, stream>>>(x, pmin, pmax);
  kan_finalize<<<64, 256, 0, stream>>>(pmin, pmax, g1, b1, m1, v1, g2, b2, m2, v2,
                                       scalev, bkn, bscv, bshv, sscv, sshv);
  kan_buildw<<<256, 256, 0, stream>>>(spline_w, spline_s, base_w, scalev, Bt, C0);
  kan_gemm<<<512, 256, 0, stream>>>(x, Bt, bkn, C0, bscv, bshv, sscv, sshv, out);
}